// Round 1
// baseline (149.885 us; speedup 1.0000x reference)
//
#include <hip/hip_runtime.h>
#include <hip/hip_bf16.h>

// EDMultiheadRetention: S=128, D=4096, H=32, hd=128
// out  = gelu(tril(q k^T) v + q (kvs*alpha^S))   (S, D)
// nkvs = kvs*alpha^S + k^T v                      (H, hd, hd)
// q,k pre-scaled per (head, channel): alpha^(s-127)/64 and alpha^(127-s)/64

typedef __bf16 bf16x8 __attribute__((ext_vector_type(8)));
typedef float f32x4 __attribute__((ext_vector_type(4)));

static __device__ __forceinline__ f32x4 mfma_bf16(bf16x8 a, bf16x8 b, f32x4 c) {
  return __builtin_amdgcn_mfma_f32_16x16x32_bf16(a, b, c, 0, 0, 0);
}

static __device__ __forceinline__ bf16x8 cvt8(float4 lo, float4 hi) {
  return (bf16x8){(__bf16)lo.x, (__bf16)lo.y, (__bf16)lo.z, (__bf16)lo.w,
                  (__bf16)hi.x, (__bf16)hi.y, (__bf16)hi.z, (__bf16)hi.w};
}

// ---------------- kernel 1: cast x (128x4096 f32) -> bf16 ----------------
__global__ __launch_bounds__(256) void cast_x_kernel(const float* __restrict__ x,
                                                     __bf16* __restrict__ xb) {
  const int i = (blockIdx.x * 256 + threadIdx.x) * 8;
  float4 a = *(const float4*)(x + i);
  float4 b = *(const float4*)(x + i + 4);
  *(bf16x8*)(xb + i) = cvt8(a, b);
}

// ---------------- kernel 2: qkv = x @ W^T, decay fused in epilogue --------
// One wave per 16 output columns, full M=128 (8 m-frags). W read exactly once.
struct Stage {
  bf16x8 a[8];
  float4 w0, w1;
};

#define LOAD_STAGE(S, K)                                             \
  do {                                                               \
    const int kk_ = (K) + g8;                                        \
    (S).w0 = *(const float4*)(wrow + kk_);                           \
    (S).w1 = *(const float4*)(wrow + kk_ + 4);                       \
    _Pragma("unroll") for (int mf_ = 0; mf_ < 8; ++mf_)              \
        (S).a[mf_] = *(const bf16x8*)(xrow + mf_ * 16 * 4096 + kk_); \
  } while (0)

#define MFMA_STAGE(S)                                                \
  do {                                                               \
    bf16x8 b_ = cvt8((S).w0, (S).w1);                                \
    _Pragma("unroll") for (int mf_ = 0; mf_ < 8; ++mf_)              \
        acc[mf_] = mfma_bf16((S).a[mf_], b_, acc[mf_]);              \
  } while (0)

__global__ __launch_bounds__(64) void gemm_qkv_kernel(const __bf16* __restrict__ xb,
                                                      const float* __restrict__ W,
                                                      const float* __restrict__ alpha,
                                                      float* __restrict__ qkv) {
  const int lane = threadIdx.x;
  const int r0 = lane & 15;
  const int g8 = (lane >> 4) << 3;
  const int rr = (lane >> 4) << 2;
  const int n = blockIdx.x * 16 + r0;  // output feature column
  const float* wrow = W + (size_t)n * 4096;
  const __bf16* xrow = xb + r0 * 4096;

  f32x4 acc[8];
#pragma unroll
  for (int i = 0; i < 8; ++i) acc[i] = (f32x4){0.f, 0.f, 0.f, 0.f};

  Stage sA, sB;
  LOAD_STAGE(sA, 0);
  LOAD_STAGE(sB, 32);
  for (int k0 = 0; k0 < 4096 - 64; k0 += 64) {
    Stage t0, t1;
    LOAD_STAGE(t0, k0 + 64);
    MFMA_STAGE(sA);
    LOAD_STAGE(t1, k0 + 96);
    MFMA_STAGE(sB);
    sA = t0;
    sB = t1;
  }
  MFMA_STAGE(sA);
  MFMA_STAGE(sB);

  // epilogue: apply per-(head,channel) decay to q and k parts, write f32
  const int which = n >> 12;      // 0=q 1=k 2=v
  const int hd_idx = n & 4095;    // h*128 + d
  const float la = log2f(alpha[hd_idx]);
#pragma unroll
  for (int mf = 0; mf < 8; ++mf) {
#pragma unroll
    for (int r = 0; r < 4; ++r) {
      const int s = mf * 16 + rr + r;
      float v = acc[mf][r];
      if (which == 0)
        v *= exp2f((float)(s - 127) * la) * 0.015625f;
      else if (which == 1)
        v *= exp2f((float)(127 - s) * la) * 0.015625f;
      qkv[(size_t)s * 12288 + n] = v;
    }
  }
}

// ---------------- kernel 3: per-head retention ----------------------------
// grid = 128 blocks (head h = b>>2, row-quarter w = b&3), 1 wave each.
__global__ __launch_bounds__(64) void head_kernel(const float* __restrict__ qkv,
                                                  const float* __restrict__ alpha,
                                                  const float* __restrict__ kvs,
                                                  float* __restrict__ out) {
  const int h = blockIdx.x >> 2;
  const int w = blockIdx.x & 3;
  const int lane = threadIdx.x;
  const int r0 = lane & 15;
  const int g8 = (lane >> 4) << 3;
  const int rr = (lane >> 4) << 2;

  __shared__ float dS[128];              // alpha^S per channel
  __shared__ __bf16 attn_s[32][136];     // this wave's 32 attn rows (padded)

  for (int d = lane; d < 128; d += 64)
    dS[d] = exp2f(128.f * log2f(alpha[h * 128 + d]));
  __syncthreads();

  const int m_base = w * 32;
  const float* qbase = qkv + h * 128;          // q_dec[s][d] = qbase[s*12288+d]
  const float* kbase = qkv + 4096 + h * 128;   // k_dec
  const float* vbase = qkv + 8192 + h * 128;   // v

  f32x4 acc[2][8];

  // ---- phase 1: attn = tril(q k^T) for rows m_base..m_base+31
#pragma unroll
  for (int mf = 0; mf < 2; ++mf)
#pragma unroll
    for (int nf = 0; nf < 8; ++nf) acc[mf][nf] = (f32x4){0.f, 0.f, 0.f, 0.f};

  for (int k0 = 0; k0 < 128; k0 += 32) {
    const int kk = k0 + g8;
    bf16x8 a[2];
#pragma unroll
    for (int mf = 0; mf < 2; ++mf) {
      const float* p = qbase + (size_t)(m_base + mf * 16 + r0) * 12288 + kk;
      a[mf] = cvt8(*(const float4*)p, *(const float4*)(p + 4));
    }
#pragma unroll
    for (int nf = 0; nf < 8; ++nf) {
      const float* p = kbase + (size_t)(nf * 16 + r0) * 12288 + kk;
      bf16x8 b = cvt8(*(const float4*)p, *(const float4*)(p + 4));
#pragma unroll
      for (int mf = 0; mf < 2; ++mf) acc[mf][nf] = mfma_bf16(a[mf], b, acc[mf][nf]);
    }
  }
  // causal mask + stash as bf16 in LDS (wave-local rows)
#pragma unroll
  for (int mf = 0; mf < 2; ++mf)
#pragma unroll
    for (int nf = 0; nf < 8; ++nf)
#pragma unroll
      for (int r = 0; r < 4; ++r) {
        const int i = m_base + mf * 16 + rr + r;
        const int j = nf * 16 + r0;
        const float v = (j <= i) ? acc[mf][nf][r] : 0.f;
        attn_s[mf * 16 + rr + r][j] = (__bf16)v;
      }
  __syncthreads();

  // ---- phase 2: out = gelu(attn @ v + q @ (kvs*dS))
#pragma unroll
  for (int mf = 0; mf < 2; ++mf)
#pragma unroll
    for (int nf = 0; nf < 8; ++nf) acc[mf][nf] = (f32x4){0.f, 0.f, 0.f, 0.f};

  for (int k0 = 0; k0 < 128; k0 += 32) {  // K = attn cols j
    const int kk = k0 + g8;
    bf16x8 a[2];
#pragma unroll
    for (int mf = 0; mf < 2; ++mf)
      a[mf] = *(const bf16x8*)(&attn_s[mf * 16 + r0][kk]);
#pragma unroll
    for (int nf = 0; nf < 8; ++nf) {
      const int d2 = nf * 16 + r0;
      bf16x8 b;
#pragma unroll
      for (int jj = 0; jj < 8; ++jj)
        b[jj] = (__bf16)vbase[(size_t)(kk + jj) * 12288 + d2];
#pragma unroll
      for (int mf = 0; mf < 2; ++mf) acc[mf][nf] = mfma_bf16(a[mf], b, acc[mf][nf]);
    }
  }
  for (int k0 = 0; k0 < 128; k0 += 32) {  // K = channels d (q @ kvs*dS)
    const int kk = k0 + g8;
    bf16x8 a[2];
#pragma unroll
    for (int mf = 0; mf < 2; ++mf) {
      const float* p = qbase + (size_t)(m_base + mf * 16 + r0) * 12288 + kk;
      a[mf] = cvt8(*(const float4*)p, *(const float4*)(p + 4));
    }
#pragma unroll
    for (int nf = 0; nf < 8; ++nf) {
      const int d2 = nf * 16 + r0;
      bf16x8 b;
#pragma unroll
      for (int jj = 0; jj < 8; ++jj)
        b[jj] = (__bf16)(kvs[h * 16384 + (size_t)(kk + jj) * 128 + d2] * dS[kk + jj]);
#pragma unroll
      for (int mf = 0; mf < 2; ++mf) acc[mf][nf] = mfma_bf16(a[mf], b, acc[mf][nf]);
    }
  }
  // gelu (tanh approx, matches jax.nn.gelu default) + store
#pragma unroll
  for (int mf = 0; mf < 2; ++mf)
#pragma unroll
    for (int nf = 0; nf < 8; ++nf)
#pragma unroll
      for (int r = 0; r < 4; ++r) {
        const int s = m_base + mf * 16 + rr + r;
        const int d2 = nf * 16 + r0;
        const float y = acc[mf][nf][r];
        const float u = 0.7978845608028654f * (y + 0.044715f * y * y * y);
        out[(size_t)s * 4096 + h * 128 + d2] = 0.5f * y * (1.f + tanhf(u));
      }

  // ---- phase 3: new_kvs rows i = m_base..m_base+31
#pragma unroll
  for (int mf = 0; mf < 2; ++mf)
#pragma unroll
    for (int nf = 0; nf < 8; ++nf) acc[mf][nf] = (f32x4){0.f, 0.f, 0.f, 0.f};

  for (int k0 = 0; k0 < 128; k0 += 32) {  // K = seq s
    const int kk = k0 + g8;
    bf16x8 a[2];
#pragma unroll
    for (int mf = 0; mf < 2; ++mf) {
      const int i = m_base + mf * 16 + r0;
#pragma unroll
      for (int jj = 0; jj < 8; ++jj)
        a[mf][jj] = (__bf16)kbase[(size_t)(kk + jj) * 12288 + i];
    }
#pragma unroll
    for (int nf = 0; nf < 8; ++nf) {
      const int j = nf * 16 + r0;
      bf16x8 b;
#pragma unroll
      for (int jj = 0; jj < 8; ++jj)
        b[jj] = (__bf16)vbase[(size_t)(kk + jj) * 12288 + j];
#pragma unroll
      for (int mf = 0; mf < 2; ++mf) acc[mf][nf] = mfma_bf16(a[mf], b, acc[mf][nf]);
    }
  }
#pragma unroll
  for (int mf = 0; mf < 2; ++mf)
#pragma unroll
    for (int nf = 0; nf < 8; ++nf)
#pragma unroll
      for (int r = 0; r < 4; ++r) {
        const int i = m_base + mf * 16 + rr + r;
        const int j = nf * 16 + r0;
        const float v = acc[mf][nf][r] + kvs[h * 16384 + (size_t)i * 128 + j] * dS[i];
        out[524288 + h * 16384 + (size_t)i * 128 + j] = v;
      }
}

extern "C" void kernel_launch(void* const* d_in, const int* in_sizes, int n_in,
                              void* d_out, int out_size, void* d_ws, size_t ws_size,
                              hipStream_t stream) {
  const float* x = (const float*)d_in[0];       // (128, 4096)
  const float* W = (const float*)d_in[1];       // (12288, 4096)
  const float* alpha = (const float*)d_in[2];   // (32, 128)
  const float* kvs = (const float*)d_in[3];     // (32, 128, 128)
  float* out = (float*)d_out;                   // 524288 + 524288 f32

  __bf16* xb = (__bf16*)d_ws;                            // 1 MB
  float* qkv = (float*)((char*)d_ws + (1 << 20));        // 6 MB

  cast_x_kernel<<<256, 256, 0, stream>>>(x, xb);
  gemm_qkv_kernel<<<768, 64, 0, stream>>>(xb, W, alpha, qkv);
  head_kernel<<<128, 64, 0, stream>>>(qkv, alpha, kvs, out);
}

// Round 2
// 103.878 us; speedup vs baseline: 1.4429x; 1.4429x over previous
//
#include <hip/hip_runtime.h>
#include <hip/hip_bf16.h>

// EDMultiheadRetention: S=128, D=4096, H=32, hd=128
// Pipeline: cast_x -> prep_kvs -> gemm_split (partials) -> reduce (decay+layouts) -> heads

typedef __bf16 bf16x8 __attribute__((ext_vector_type(8)));
typedef float f32x4 __attribute__((ext_vector_type(4)));

typedef __attribute__((address_space(1))) const unsigned g_u32;
typedef __attribute__((address_space(3))) unsigned l_u32;

static __device__ __forceinline__ f32x4 mfma_bf16(bf16x8 a, bf16x8 b, f32x4 c) {
  return __builtin_amdgcn_mfma_f32_16x16x32_bf16(a, b, c, 0, 0, 0);
}

static __device__ __forceinline__ bf16x8 cvt8(float4 lo, float4 hi) {
  return (bf16x8){(__bf16)lo.x, (__bf16)lo.y, (__bf16)lo.z, (__bf16)lo.w,
                  (__bf16)hi.x, (__bf16)hi.y, (__bf16)hi.z, (__bf16)hi.w};
}

// ---------------- kernel 1: cast x (128x4096 f32) -> bf16 ----------------
__global__ __launch_bounds__(256) void cast_x_kernel(const float* __restrict__ x,
                                                     __bf16* __restrict__ xb) {
  const int i = (blockIdx.x * 256 + threadIdx.x) * 8;
  float4 a = *(const float4*)(x + i);
  float4 b = *(const float4*)(x + i + 4);
  *(bf16x8*)(xb + i) = cvt8(a, b);
}

// ---------------- kernel 2: kvsT[h][j][d] = (kvs[h][d][j]*alpha[h][d]^128) bf16
__global__ __launch_bounds__(256) void prep_kvs_kernel(const float* __restrict__ kvs,
                                                       const float* __restrict__ alpha,
                                                       __bf16* __restrict__ kvsT) {
  __shared__ float lds[32][129];
  const int h = blockIdx.x >> 2, dq = blockIdx.x & 3;
  const int tid = threadIdx.x;
  const int j = tid & 127, dg = tid >> 7;
  const int d0 = dq * 32;
#pragma unroll
  for (int i = 0; i < 16; ++i) {
    const int dloc = dg * 16 + i;
    const int d = d0 + dloc;
    const float dS = exp2f(128.f * log2f(alpha[h * 128 + d]));
    lds[dloc][j] = kvs[(size_t)h * 16384 + d * 128 + j] * dS;
  }
  __syncthreads();
  const int jj = tid >> 1, dh = tid & 1;
  bf16x8 a0, a1;
#pragma unroll
  for (int i = 0; i < 8; ++i) a0[i] = (__bf16)lds[dh * 16 + i][jj];
#pragma unroll
  for (int i = 0; i < 8; ++i) a1[i] = (__bf16)lds[dh * 16 + 8 + i][jj];
  *(bf16x8*)(kvsT + (size_t)h * 16384 + jj * 128 + d0 + dh * 16) = a0;
  *(bf16x8*)(kvsT + (size_t)h * 16384 + jj * 128 + d0 + dh * 16 + 8) = a1;
}

// ---------------- kernel 3: split-K GEMM: P[ks][s][n] = x @ W^T (partial) ---
// block = 256 thr (4 waves, 2x2), tile M=128 x N=64, BK=32, LDS double-buffered.
__global__ __launch_bounds__(256) void gemm_split_kernel(const __bf16* __restrict__ xb,
                                                         const float* __restrict__ W,
                                                         float* __restrict__ P,
                                                         int kc_len) {
  __shared__ __bf16 Ald[2][128 * 32];  // [row][4 chunks of 8 bf16], chunk XOR-swizzled
  __shared__ __bf16 Bld[2][64 * 32];

  const int tid = threadIdx.x;
  const int wid = tid >> 6, lane = tid & 63;
  const int r0 = lane & 15, l4 = lane >> 4;
  const int rr = l4 << 2;
  const int nt = blockIdx.x % 192, ks = blockIdx.x / 192;
  const int n0 = nt * 64;
  const int kb0 = ks * kc_len;
  const int wm = wid & 1, wn = wid >> 1;

  // B staging role: thread -> (col n, physical chunk p)
  const int bn = tid >> 2, bp = tid & 3;
  const int blc = bp ^ (bn & 3);
  const float* wsrc = W + (size_t)(n0 + bn) * 4096 + kb0 + blc * 8;

  // A staging roles (2 gload_lds per thread)
  int a_r[2], a_k[2];
#pragma unroll
  for (int i = 0; i < 2; ++i) {
    const int idx = i * 256 + tid;
    a_r[i] = idx >> 2;
    const int p = idx & 3;
    a_k[i] = ((p ^ (a_r[i] & 3)) << 3);
  }

  f32x4 acc[4][2];
#pragma unroll
  for (int mf = 0; mf < 4; ++mf)
#pragma unroll
    for (int nf = 0; nf < 2; ++nf) acc[mf][nf] = (f32x4){0.f, 0.f, 0.f, 0.f};

  // prologue: stage tile 0 into buf 0
  {
#pragma unroll
    for (int i = 0; i < 2; ++i) {
      const __bf16* src = xb + a_r[i] * 4096 + kb0 + a_k[i];
      __builtin_amdgcn_global_load_lds((g_u32*)(const void*)src,
                                       (l_u32*)(void*)((char*)&Ald[0][0] + i * 4096 + wid * 1024),
                                       16, 0, 0);
    }
    float4 lo = *(const float4*)(wsrc);
    float4 hi = *(const float4*)(wsrc + 4);
    *(bf16x8*)((char*)&Bld[0][0] + tid * 16) = cvt8(lo, hi);
  }
  __syncthreads();

  const int iters = kc_len / 32;
  for (int kt = 0; kt < iters; ++kt) {
    const int cur = kt & 1, nxt = cur ^ 1;
    const bool has_next = (kt + 1 < iters);
    float4 wlo, whi;
    if (has_next) {
      const int kb = (kt + 1) * 32;
#pragma unroll
      for (int i = 0; i < 2; ++i) {
        const __bf16* src = xb + a_r[i] * 4096 + kb0 + kb + a_k[i];
        __builtin_amdgcn_global_load_lds((g_u32*)(const void*)src,
                                         (l_u32*)(void*)((char*)&Ald[nxt][0] + i * 4096 + wid * 1024),
                                         16, 0, 0);
      }
      wlo = *(const float4*)(wsrc + kb);
      whi = *(const float4*)(wsrc + kb + 4);
    }

    bf16x8 af[4], bfr[2];
#pragma unroll
    for (int mf = 0; mf < 4; ++mf) {
      const int row = wm * 64 + mf * 16 + r0;
      const int p = l4 ^ (row & 3);
      af[mf] = *(const bf16x8*)((const char*)&Ald[cur][0] + row * 64 + p * 16);
    }
#pragma unroll
    for (int nf = 0; nf < 2; ++nf) {
      const int nn = wn * 32 + nf * 16 + r0;
      const int p = l4 ^ (nn & 3);
      bfr[nf] = *(const bf16x8*)((const char*)&Bld[cur][0] + nn * 64 + p * 16);
    }
#pragma unroll
    for (int mf = 0; mf < 4; ++mf)
#pragma unroll
      for (int nf = 0; nf < 2; ++nf) acc[mf][nf] = mfma_bf16(af[mf], bfr[nf], acc[mf][nf]);

    if (has_next) {
      *(bf16x8*)((char*)&Bld[nxt][0] + tid * 16) = cvt8(wlo, whi);
    }
    __syncthreads();
  }

  // epilogue: write partials P[ks][s][n]
#pragma unroll
  for (int mf = 0; mf < 4; ++mf)
#pragma unroll
    for (int nf = 0; nf < 2; ++nf)
#pragma unroll
      for (int r = 0; r < 4; ++r) {
        const int s = wm * 64 + mf * 16 + rr + r;
        const int n = n0 + wn * 32 + nf * 16 + r0;
        P[(size_t)ks * 1572864 + (size_t)s * 12288 + n] = acc[mf][nf][r];
      }
}

// ---------------- kernel 4: reduce partials, apply decay, emit bf16 layouts
// qd/kd [h][s][d], kdT/vT [h][d][s]
__global__ __launch_bounds__(256) void reduce_kernel(const float* __restrict__ P,
                                                     const float* __restrict__ alpha,
                                                     __bf16* __restrict__ qd,
                                                     __bf16* __restrict__ kd,
                                                     __bf16* __restrict__ kdT,
                                                     __bf16* __restrict__ vT, int KS) {
  __shared__ float lds[32][129];
  const int bid = blockIdx.x;
  const int which = bid >> 7;  // 0=q 1=k 2=v
  const int rem = bid & 127;
  const int h = rem >> 2, sq = rem & 3;
  const int tid = threadIdx.x;
  const int d = tid & 127, sg = tid >> 7;
  const int n = which * 4096 + h * 128 + d;
  const int s0 = sq * 32;
  const float la = log2f(alpha[h * 128 + d]);

#pragma unroll 1
  for (int si = 0; si < 16; ++si) {
    const int s = s0 + sg * 16 + si;
    float val = 0.f;
    for (int ksi = 0; ksi < KS; ++ksi)
      val += P[(size_t)ksi * 1572864 + (size_t)s * 12288 + n];
    if (which == 0)
      val *= exp2f((float)(s - 127) * la - 6.0f);
    else if (which == 1)
      val *= exp2f((float)(127 - s) * la - 6.0f);
    lds[sg * 16 + si][d] = val;
    if (which == 0)
      qd[(size_t)h * 16384 + s * 128 + d] = (__bf16)val;
    else if (which == 1)
      kd[(size_t)h * 16384 + s * 128 + d] = (__bf16)val;
  }
  if (which == 0) return;
  __syncthreads();
  __bf16* outT = (which == 1 ? kdT : vT) + (size_t)h * 16384;
  const int dd = tid >> 1, sh = tid & 1;
  bf16x8 v0, v1;
#pragma unroll
  for (int i = 0; i < 8; ++i) v0[i] = (__bf16)lds[sh * 16 + i][dd];
#pragma unroll
  for (int i = 0; i < 8; ++i) v1[i] = (__bf16)lds[sh * 16 + 8 + i][dd];
  *(bf16x8*)(outT + dd * 128 + s0 + sh * 16) = v0;
  *(bf16x8*)(outT + dd * 128 + s0 + sh * 16 + 8) = v1;
}

// ---------------- kernel 5: per-head retention (all contiguous bf16 loads) --
// bid<128: out rows; bid>=128: new_kvs rows. 128 threads (2 waves).
__global__ __launch_bounds__(128) void heads_kernel(const __bf16* __restrict__ qd,
                                                    const __bf16* __restrict__ kd,
                                                    const __bf16* __restrict__ kdT,
                                                    const __bf16* __restrict__ vT,
                                                    const __bf16* __restrict__ kvsT,
                                                    const float* __restrict__ kvs,
                                                    const float* __restrict__ alpha,
                                                    float* __restrict__ out) {
  const int bid = blockIdx.x;
  const int tid = threadIdx.x;
  const int wid = tid >> 6, lane = tid & 63;
  const int r0 = lane & 15, l4 = lane >> 4;
  const int g8 = l4 << 3, rr = l4 << 2;

  if (bid < 128) {
    const int h = bid >> 2, w = bid & 3;
    const int m_base = w * 32;
    __shared__ __bf16 attn_s[32][136];
    const __bf16* qh = qd + (size_t)h * 16384;
    const __bf16* kh = kd + (size_t)h * 16384;

    f32x4 acc[2][4];
#pragma unroll
    for (int mf = 0; mf < 2; ++mf)
#pragma unroll
      for (int nf = 0; nf < 4; ++nf) acc[mf][nf] = (f32x4){0.f, 0.f, 0.f, 0.f};

    // phase 1: attn cols wid*64..+64
#pragma unroll
    for (int k0 = 0; k0 < 128; k0 += 32) {
      const int kk = k0 + g8;
      bf16x8 a[2];
#pragma unroll
      for (int mf = 0; mf < 2; ++mf)
        a[mf] = *(const bf16x8*)(qh + (m_base + mf * 16 + r0) * 128 + kk);
#pragma unroll
      for (int nf = 0; nf < 4; ++nf) {
        const int jn = wid * 64 + nf * 16 + r0;
        bf16x8 b = *(const bf16x8*)(kh + jn * 128 + kk);
#pragma unroll
        for (int mf = 0; mf < 2; ++mf) acc[mf][nf] = mfma_bf16(a[mf], b, acc[mf][nf]);
      }
    }
#pragma unroll
    for (int mf = 0; mf < 2; ++mf)
#pragma unroll
      for (int nf = 0; nf < 4; ++nf)
#pragma unroll
        for (int r = 0; r < 4; ++r) {
          const int i = m_base + mf * 16 + rr + r;
          const int j = wid * 64 + nf * 16 + r0;
          attn_s[mf * 16 + rr + r][j] = (__bf16)((j <= i) ? acc[mf][nf][r] : 0.f);
        }
    __syncthreads();

    // phase 2: out = gelu(attn @ v + q @ kvsT), d2 in wid*64..+64
#pragma unroll
    for (int mf = 0; mf < 2; ++mf)
#pragma unroll
      for (int nf = 0; nf < 4; ++nf) acc[mf][nf] = (f32x4){0.f, 0.f, 0.f, 0.f};
    const __bf16* vTh = vT + (size_t)h * 16384;
    const __bf16* kvsTh = kvsT + (size_t)h * 16384;
#pragma unroll
    for (int k0 = 0; k0 < 128; k0 += 32) {
      const int kk = k0 + g8;
      bf16x8 a[2];
#pragma unroll
      for (int mf = 0; mf < 2; ++mf)
        a[mf] = *(const bf16x8*)(&attn_s[mf * 16 + r0][kk]);
#pragma unroll
      for (int nf = 0; nf < 4; ++nf) {
        const int d2 = wid * 64 + nf * 16 + r0;
        bf16x8 b = *(const bf16x8*)(vTh + d2 * 128 + kk);
#pragma unroll
        for (int mf = 0; mf < 2; ++mf) acc[mf][nf] = mfma_bf16(a[mf], b, acc[mf][nf]);
      }
    }
#pragma unroll
    for (int k0 = 0; k0 < 128; k0 += 32) {
      const int kk = k0 + g8;
      bf16x8 a[2];
#pragma unroll
      for (int mf = 0; mf < 2; ++mf)
        a[mf] = *(const bf16x8*)(qh + (m_base + mf * 16 + r0) * 128 + kk);
#pragma unroll
      for (int nf = 0; nf < 4; ++nf) {
        const int d2 = wid * 64 + nf * 16 + r0;
        bf16x8 b = *(const bf16x8*)(kvsTh + d2 * 128 + kk);
#pragma unroll
        for (int mf = 0; mf < 2; ++mf) acc[mf][nf] = mfma_bf16(a[mf], b, acc[mf][nf]);
      }
    }
#pragma unroll
    for (int mf = 0; mf < 2; ++mf)
#pragma unroll
      for (int nf = 0; nf < 4; ++nf)
#pragma unroll
        for (int r = 0; r < 4; ++r) {
          const int s = m_base + mf * 16 + rr + r;
          const int d2 = wid * 64 + nf * 16 + r0;
          const float y = acc[mf][nf][r];
          const float u = 0.7978845608028654f * (y + 0.044715f * y * y * y);
          out[(size_t)s * 4096 + h * 128 + d2] = 0.5f * y * (1.f + tanhf(u));
        }
  } else {
    const int b2 = bid - 128;
    const int h = b2 >> 2, w = b2 & 3;
    const int m_base = w * 32;
    const __bf16* kTh = kdT + (size_t)h * 16384;
    const __bf16* vTh = vT + (size_t)h * 16384;

    f32x4 acc[2][4];
#pragma unroll
    for (int mf = 0; mf < 2; ++mf)
#pragma unroll
      for (int nf = 0; nf < 4; ++nf) acc[mf][nf] = (f32x4){0.f, 0.f, 0.f, 0.f};
#pragma unroll
    for (int k0 = 0; k0 < 128; k0 += 32) {
      const int kk = k0 + g8;
      bf16x8 a[2];
#pragma unroll
      for (int mf = 0; mf < 2; ++mf)
        a[mf] = *(const bf16x8*)(kTh + (m_base + mf * 16 + r0) * 128 + kk);
#pragma unroll
      for (int nf = 0; nf < 4; ++nf) {
        const int j = wid * 64 + nf * 16 + r0;
        bf16x8 b = *(const bf16x8*)(vTh + j * 128 + kk);
#pragma unroll
        for (int mf = 0; mf < 2; ++mf) acc[mf][nf] = mfma_bf16(a[mf], b, acc[mf][nf]);
      }
    }
#pragma unroll
    for (int mf = 0; mf < 2; ++mf)
#pragma unroll
      for (int nf = 0; nf < 4; ++nf)
#pragma unroll
        for (int r = 0; r < 4; ++r) {
          const int i = m_base + mf * 16 + rr + r;
          const int j = wid * 64 + nf * 16 + r0;
          const float dSi = exp2f(128.f * log2f(alpha[h * 128 + i]));
          const float val = acc[mf][nf][r] + kvs[(size_t)h * 16384 + i * 128 + j] * dSi;
          out[524288 + (size_t)h * 16384 + i * 128 + j] = val;
        }
  }
}

extern "C" void kernel_launch(void* const* d_in, const int* in_sizes, int n_in,
                              void* d_out, int out_size, void* d_ws, size_t ws_size,
                              hipStream_t stream) {
  const float* x = (const float*)d_in[0];      // (128, 4096)
  const float* W = (const float*)d_in[1];      // (12288, 4096)
  const float* alpha = (const float*)d_in[2];  // (32, 128)
  const float* kvs = (const float*)d_in[3];    // (32, 128, 128)
  float* out = (float*)d_out;

  char* ws = (char*)d_ws;
  __bf16* xb = (__bf16*)ws;                      // 1 MB
  __bf16* qd = (__bf16*)(ws + (1u << 20));       // 1 MB each
  __bf16* kd = (__bf16*)(ws + 2u * (1u << 20));
  __bf16* kdT = (__bf16*)(ws + 3u * (1u << 20));
  __bf16* vT = (__bf16*)(ws + 4u * (1u << 20));
  __bf16* kvsT = (__bf16*)(ws + 5u * (1u << 20));
  float* P = (float*)(ws + 6u * (1u << 20));     // KS * 6,291,456 B

  const size_t pbytes = ws_size > 6u * (1u << 20) ? ws_size - 6u * (1u << 20) : 0;
  int KS = 1;
  while (KS < 8 && (size_t)(KS * 2) * 6291456ull <= pbytes) KS *= 2;
  const int kc_len = 4096 / KS;

  cast_x_kernel<<<256, 256, 0, stream>>>(x, xb);
  prep_kvs_kernel<<<128, 256, 0, stream>>>(kvs, alpha, kvsT);
  gemm_split_kernel<<<192 * KS, 256, 0, stream>>>(xb, W, P, kc_len);
  reduce_kernel<<<384, 256, 0, stream>>>(P, alpha, qd, kd, kdT, vT, KS);
  heads_kernel<<<256, 128, 0, stream>>>(qd, kd, kdT, vT, kvsT, kvs, alpha, out);
}

// Round 3
// 78.668 us; speedup vs baseline: 1.9053x; 1.3205x over previous
//
#include <hip/hip_runtime.h>
#include <hip/hip_bf16.h>

// EDMultiheadRetention: S=128, D=4096, H=32, hd=128
// Pipeline: prep (cast x + kvsT) -> gemm_split (KS=4 partials) -> reduce (decay+layouts) -> heads

typedef __bf16 bf16x8 __attribute__((ext_vector_type(8)));
typedef float f32x4 __attribute__((ext_vector_type(4)));

typedef __attribute__((address_space(1))) const unsigned g_u32;
typedef __attribute__((address_space(3))) unsigned l_u32;

static __device__ __forceinline__ f32x4 mfma_bf16(bf16x8 a, bf16x8 b, f32x4 c) {
  return __builtin_amdgcn_mfma_f32_16x16x32_bf16(a, b, c, 0, 0, 0);
}

static __device__ __forceinline__ bf16x8 cvt8(float4 lo, float4 hi) {
  return (bf16x8){(__bf16)lo.x, (__bf16)lo.y, (__bf16)lo.z, (__bf16)lo.w,
                  (__bf16)hi.x, (__bf16)hi.y, (__bf16)hi.z, (__bf16)hi.w};
}

// ---------------- kernel 1: cast x -> bf16 (blocks 0..255), kvsT prep (256..383)
__global__ __launch_bounds__(256) void prep_kernel(const float* __restrict__ x,
                                                   __bf16* __restrict__ xb,
                                                   const float* __restrict__ kvs,
                                                   const float* __restrict__ alpha,
                                                   __bf16* __restrict__ kvsT) {
  __shared__ float lds[32][129];
  const int tid = threadIdx.x;
  if (blockIdx.x < 256) {
    const int i = (blockIdx.x * 256 + tid) * 8;
    float4 a = *(const float4*)(x + i);
    float4 b = *(const float4*)(x + i + 4);
    *(bf16x8*)(xb + i) = cvt8(a, b);
    return;
  }
  const int bid = blockIdx.x - 256;
  const int h = bid >> 2, dq = bid & 3;
  const int j = tid & 127, dg = tid >> 7;
  const int d0 = dq * 32;
#pragma unroll
  for (int i = 0; i < 16; ++i) {
    const int dloc = dg * 16 + i;
    const int d = d0 + dloc;
    const float dS = exp2f(128.f * log2f(alpha[h * 128 + d]));
    lds[dloc][j] = kvs[(size_t)h * 16384 + d * 128 + j] * dS;
  }
  __syncthreads();
  const int jj = tid >> 1, dh = tid & 1;
  bf16x8 a0, a1;
#pragma unroll
  for (int i = 0; i < 8; ++i) a0[i] = (__bf16)lds[dh * 16 + i][jj];
#pragma unroll
  for (int i = 0; i < 8; ++i) a1[i] = (__bf16)lds[dh * 16 + 8 + i][jj];
  *(bf16x8*)(kvsT + (size_t)h * 16384 + jj * 128 + d0 + dh * 16) = a0;
  *(bf16x8*)(kvsT + (size_t)h * 16384 + jj * 128 + d0 + dh * 16 + 8) = a1;
}

// ---------------- kernel 2: split-K GEMM: P[ks][s][n] = x @ W^T (partial) ---
// 256 thr (4 waves 2x2), tile M=128 x N=64, BK=64, double-buffered LDS,
// rows = 128B = 8 chunks of 16B, physical chunk p = logical c ^ (row&7).
__global__ __launch_bounds__(256) void gemm_split_kernel(const __bf16* __restrict__ xb,
                                                         const float* __restrict__ W,
                                                         float* __restrict__ P,
                                                         int kc_len) {
  __shared__ __bf16 Ald[2][128 * 64];
  __shared__ __bf16 Bld[2][64 * 64];

  const int tid = threadIdx.x;
  const int wid = tid >> 6, lane = tid & 63;
  const int r0 = lane & 15, l4 = lane >> 4, rr = l4 << 2;
  const int nt = blockIdx.x % 192, ks = blockIdx.x / 192;
  const int n0 = nt * 64;
  const int kb0 = ks * kc_len;
  const int wm = wid & 1, wn = wid >> 1;

  // A staging: 4 DMA per thread; unit u -> (row=u>>3, phys p=u&7), src chunk g=p^(row&7)
  int a_row[4], a_koff[4];
#pragma unroll
  for (int i = 0; i < 4; ++i) {
    const int u = i * 256 + tid;
    a_row[i] = u >> 3;
    a_koff[i] = ((u & 7) ^ (a_row[i] & 7)) << 3;
  }
  // B staging: 2 units per thread (reg-staged f32 -> bf16 -> swizzled ds_write)
  int b_row[2], b_koff[2], b_elem[2];
#pragma unroll
  for (int i = 0; i < 2; ++i) {
    const int u = i * 256 + tid;
    b_row[i] = u >> 3;
    const int p = u & 7;
    b_koff[i] = (p ^ (b_row[i] & 7)) << 3;
    b_elem[i] = b_row[i] * 64 + p * 8;
  }

  // fragment read offsets (elements)
  int a_off[4][2], b_off[2][2];
#pragma unroll
  for (int mf = 0; mf < 4; ++mf)
#pragma unroll
    for (int kh = 0; kh < 2; ++kh) {
      const int row = wm * 64 + mf * 16 + r0;
      const int p = (kh * 4 + l4) ^ (row & 7);
      a_off[mf][kh] = row * 64 + p * 8;
    }
#pragma unroll
  for (int nf = 0; nf < 2; ++nf)
#pragma unroll
    for (int kh = 0; kh < 2; ++kh) {
      const int row = wn * 32 + nf * 16 + r0;
      const int p = (kh * 4 + l4) ^ (row & 7);
      b_off[nf][kh] = row * 64 + p * 8;
    }

  f32x4 acc[4][2];
#pragma unroll
  for (int mf = 0; mf < 4; ++mf)
#pragma unroll
    for (int nf = 0; nf < 2; ++nf) acc[mf][nf] = (f32x4){0.f, 0.f, 0.f, 0.f};

  // prologue: stage tile 0 into buf 0
  {
#pragma unroll
    for (int i = 0; i < 4; ++i) {
      const __bf16* src = xb + a_row[i] * 4096 + kb0 + a_koff[i];
      __builtin_amdgcn_global_load_lds((g_u32*)(const void*)src,
                                       (l_u32*)(void*)((char*)&Ald[0][0] + i * 4096 + wid * 1024),
                                       16, 0, 0);
    }
#pragma unroll
    for (int i = 0; i < 2; ++i) {
      const float* s = W + (size_t)(n0 + b_row[i]) * 4096 + kb0 + b_koff[i];
      float4 lo = *(const float4*)(s);
      float4 hi = *(const float4*)(s + 4);
      *(bf16x8*)(&Bld[0][b_elem[i]]) = cvt8(lo, hi);
    }
  }
  __syncthreads();

  const int iters = kc_len >> 6;
  for (int kt = 0; kt < iters; ++kt) {
    const int cur = kt & 1, nxt = cur ^ 1;
    const bool has_next = (kt + 1 < iters);
    float4 wlo[2], whi[2];
    if (has_next) {
      const int kb = kb0 + (kt + 1) * 64;
#pragma unroll
      for (int i = 0; i < 4; ++i) {
        const __bf16* src = xb + a_row[i] * 4096 + kb + a_koff[i];
        __builtin_amdgcn_global_load_lds((g_u32*)(const void*)src,
                                         (l_u32*)(void*)((char*)&Ald[nxt][0] + i * 4096 + wid * 1024),
                                         16, 0, 0);
      }
#pragma unroll
      for (int i = 0; i < 2; ++i) {
        const float* s = W + (size_t)(n0 + b_row[i]) * 4096 + kb + b_koff[i];
        wlo[i] = *(const float4*)(s);
        whi[i] = *(const float4*)(s + 4);
      }
    }

    bf16x8 af[4][2], bfr[2][2];
#pragma unroll
    for (int kh = 0; kh < 2; ++kh) {
#pragma unroll
      for (int mf = 0; mf < 4; ++mf) af[mf][kh] = *(const bf16x8*)(&Ald[cur][a_off[mf][kh]]);
#pragma unroll
      for (int nf = 0; nf < 2; ++nf) bfr[nf][kh] = *(const bf16x8*)(&Bld[cur][b_off[nf][kh]]);
    }
#pragma unroll
    for (int kh = 0; kh < 2; ++kh)
#pragma unroll
      for (int mf = 0; mf < 4; ++mf)
#pragma unroll
        for (int nf = 0; nf < 2; ++nf)
          acc[mf][nf] = mfma_bf16(af[mf][kh], bfr[nf][kh], acc[mf][nf]);

    if (has_next) {
#pragma unroll
      for (int i = 0; i < 2; ++i) *(bf16x8*)(&Bld[nxt][b_elem[i]]) = cvt8(wlo[i], whi[i]);
    }
    __syncthreads();
  }

  // epilogue: write partials P[ks][s][n]
#pragma unroll
  for (int mf = 0; mf < 4; ++mf)
#pragma unroll
    for (int nf = 0; nf < 2; ++nf)
#pragma unroll
      for (int r = 0; r < 4; ++r) {
        const int s = wm * 64 + mf * 16 + rr + r;
        const int n = n0 + wn * 32 + nf * 16 + r0;
        P[(size_t)ks * 1572864 + (size_t)s * 12288 + n] = acc[mf][nf][r];
      }
}

// ---------------- kernel 3: reduce partials, apply decay, emit bf16 layouts
// qd/kd [h][s][d], kdT/vT [h][d][s]
__global__ __launch_bounds__(256) void reduce_kernel(const float* __restrict__ P,
                                                     const float* __restrict__ alpha,
                                                     __bf16* __restrict__ qd,
                                                     __bf16* __restrict__ kd,
                                                     __bf16* __restrict__ kdT,
                                                     __bf16* __restrict__ vT, int KS) {
  __shared__ float lds[32][129];
  const int bid = blockIdx.x;
  const int which = bid >> 7;  // 0=q 1=k 2=v
  const int rem = bid & 127;
  const int h = rem >> 2, sq = rem & 3;
  const int tid = threadIdx.x;
  const int d = tid & 127, sg = tid >> 7;
  const int n = which * 4096 + h * 128 + d;
  const int s0 = sq * 32;
  const float la = log2f(alpha[h * 128 + d]);

#pragma unroll 4
  for (int si = 0; si < 16; ++si) {
    const int s = s0 + sg * 16 + si;
    float val = 0.f;
#pragma unroll
    for (int ksi = 0; ksi < 4; ++ksi)
      if (ksi < KS) val += P[(size_t)ksi * 1572864 + (size_t)s * 12288 + n];
    if (which == 0)
      val *= exp2f((float)(s - 127) * la - 6.0f);
    else if (which == 1)
      val *= exp2f((float)(127 - s) * la - 6.0f);
    lds[sg * 16 + si][d] = val;
    if (which == 0)
      qd[(size_t)h * 16384 + s * 128 + d] = (__bf16)val;
    else if (which == 1)
      kd[(size_t)h * 16384 + s * 128 + d] = (__bf16)val;
  }
  if (which == 0) return;
  __syncthreads();
  __bf16* outT = (which == 1 ? kdT : vT) + (size_t)h * 16384;
  const int dd = tid >> 1, sh = tid & 1;
  bf16x8 v0, v1;
#pragma unroll
  for (int i = 0; i < 8; ++i) v0[i] = (__bf16)lds[sh * 16 + i][dd];
#pragma unroll
  for (int i = 0; i < 8; ++i) v1[i] = (__bf16)lds[sh * 16 + 8 + i][dd];
  *(bf16x8*)(outT + dd * 128 + s0 + sh * 16) = v0;
  *(bf16x8*)(outT + dd * 128 + s0 + sh * 16 + 8) = v1;
}

// ---------------- kernel 4: per-head retention (all contiguous bf16 loads) --
// bid<128: out rows; bid>=128: new_kvs rows. 128 threads (2 waves).
__global__ __launch_bounds__(128) void heads_kernel(const __bf16* __restrict__ qd,
                                                    const __bf16* __restrict__ kd,
                                                    const __bf16* __restrict__ kdT,
                                                    const __bf16* __restrict__ vT,
                                                    const __bf16* __restrict__ kvsT,
                                                    const float* __restrict__ kvs,
                                                    const float* __restrict__ alpha,
                                                    float* __restrict__ out) {
  const int bid = blockIdx.x;
  const int tid = threadIdx.x;
  const int wid = tid >> 6, lane = tid & 63;
  const int r0 = lane & 15, l4 = lane >> 4;
  const int g8 = l4 << 3, rr = l4 << 2;

  if (bid < 128) {
    const int h = bid >> 2, w = bid & 3;
    const int m_base = w * 32;
    __shared__ __bf16 attn_s[32][136];
    const __bf16* qh = qd + (size_t)h * 16384;
    const __bf16* kh = kd + (size_t)h * 16384;

    f32x4 acc[2][4];
#pragma unroll
    for (int mf = 0; mf < 2; ++mf)
#pragma unroll
      for (int nf = 0; nf < 4; ++nf) acc[mf][nf] = (f32x4){0.f, 0.f, 0.f, 0.f};

    // phase 1: attn cols wid*64..+64
#pragma unroll
    for (int k0 = 0; k0 < 128; k0 += 32) {
      const int kk = k0 + g8;
      bf16x8 a[2];
#pragma unroll
      for (int mf = 0; mf < 2; ++mf)
        a[mf] = *(const bf16x8*)(qh + (m_base + mf * 16 + r0) * 128 + kk);
#pragma unroll
      for (int nf = 0; nf < 4; ++nf) {
        const int jn = wid * 64 + nf * 16 + r0;
        bf16x8 b = *(const bf16x8*)(kh + jn * 128 + kk);
#pragma unroll
        for (int mf = 0; mf < 2; ++mf) acc[mf][nf] = mfma_bf16(a[mf], b, acc[mf][nf]);
      }
    }
#pragma unroll
    for (int mf = 0; mf < 2; ++mf)
#pragma unroll
      for (int nf = 0; nf < 4; ++nf)
#pragma unroll
        for (int r = 0; r < 4; ++r) {
          const int i = m_base + mf * 16 + rr + r;
          const int j = wid * 64 + nf * 16 + r0;
          attn_s[mf * 16 + rr + r][j] = (__bf16)((j <= i) ? acc[mf][nf][r] : 0.f);
        }
    __syncthreads();

    // phase 2: out = gelu(attn @ v + q @ kvsT), d2 in wid*64..+64
#pragma unroll
    for (int mf = 0; mf < 2; ++mf)
#pragma unroll
      for (int nf = 0; nf < 4; ++nf) acc[mf][nf] = (f32x4){0.f, 0.f, 0.f, 0.f};
    const __bf16* vTh = vT + (size_t)h * 16384;
    const __bf16* kvsTh = kvsT + (size_t)h * 16384;
#pragma unroll
    for (int k0 = 0; k0 < 128; k0 += 32) {
      const int kk = k0 + g8;
      bf16x8 a[2];
#pragma unroll
      for (int mf = 0; mf < 2; ++mf)
        a[mf] = *(const bf16x8*)(&attn_s[mf * 16 + r0][kk]);
#pragma unroll
      for (int nf = 0; nf < 4; ++nf) {
        const int d2 = wid * 64 + nf * 16 + r0;
        bf16x8 b = *(const bf16x8*)(vTh + d2 * 128 + kk);
#pragma unroll
        for (int mf = 0; mf < 2; ++mf) acc[mf][nf] = mfma_bf16(a[mf], b, acc[mf][nf]);
      }
    }
#pragma unroll
    for (int k0 = 0; k0 < 128; k0 += 32) {
      const int kk = k0 + g8;
      bf16x8 a[2];
#pragma unroll
      for (int mf = 0; mf < 2; ++mf)
        a[mf] = *(const bf16x8*)(qh + (m_base + mf * 16 + r0) * 128 + kk);
#pragma unroll
      for (int nf = 0; nf < 4; ++nf) {
        const int d2 = wid * 64 + nf * 16 + r0;
        bf16x8 b = *(const bf16x8*)(kvsTh + d2 * 128 + kk);
#pragma unroll
        for (int mf = 0; mf < 2; ++mf) acc[mf][nf] = mfma_bf16(a[mf], b, acc[mf][nf]);
      }
    }
#pragma unroll
    for (int mf = 0; mf < 2; ++mf)
#pragma unroll
      for (int nf = 0; nf < 4; ++nf)
#pragma unroll
        for (int r = 0; r < 4; ++r) {
          const int s = m_base + mf * 16 + rr + r;
          const int d2 = wid * 64 + nf * 16 + r0;
          const float y = acc[mf][nf][r];
          const float u = 0.7978845608028654f * (y + 0.044715f * y * y * y);
          out[(size_t)s * 4096 + h * 128 + d2] = 0.5f * y * (1.f + tanhf(u));
        }
  } else {
    const int b2 = bid - 128;
    const int h = b2 >> 2, w = b2 & 3;
    const int m_base = w * 32;
    const __bf16* kTh = kdT + (size_t)h * 16384;
    const __bf16* vTh = vT + (size_t)h * 16384;

    f32x4 acc[2][4];
#pragma unroll
    for (int mf = 0; mf < 2; ++mf)
#pragma unroll
      for (int nf = 0; nf < 4; ++nf) acc[mf][nf] = (f32x4){0.f, 0.f, 0.f, 0.f};
#pragma unroll
    for (int k0 = 0; k0 < 128; k0 += 32) {
      const int kk = k0 + g8;
      bf16x8 a[2];
#pragma unroll
      for (int mf = 0; mf < 2; ++mf)
        a[mf] = *(const bf16x8*)(kTh + (m_base + mf * 16 + r0) * 128 + kk);
#pragma unroll
      for (int nf = 0; nf < 4; ++nf) {
        const int j = wid * 64 + nf * 16 + r0;
        bf16x8 b = *(const bf16x8*)(vTh + j * 128 + kk);
#pragma unroll
        for (int mf = 0; mf < 2; ++mf) acc[mf][nf] = mfma_bf16(a[mf], b, acc[mf][nf]);
      }
    }
#pragma unroll
    for (int mf = 0; mf < 2; ++mf)
#pragma unroll
      for (int nf = 0; nf < 4; ++nf)
#pragma unroll
        for (int r = 0; r < 4; ++r) {
          const int i = m_base + mf * 16 + rr + r;
          const int j = wid * 64 + nf * 16 + r0;
          const float dSi = exp2f(128.f * log2f(alpha[h * 128 + i]));
          const float val = acc[mf][nf][r] + kvs[(size_t)h * 16384 + i * 128 + j] * dSi;
          out[524288 + (size_t)h * 16384 + i * 128 + j] = val;
        }
  }
}

extern "C" void kernel_launch(void* const* d_in, const int* in_sizes, int n_in,
                              void* d_out, int out_size, void* d_ws, size_t ws_size,
                              hipStream_t stream) {
  const float* x = (const float*)d_in[0];      // (128, 4096)
  const float* W = (const float*)d_in[1];      // (12288, 4096)
  const float* alpha = (const float*)d_in[2];  // (32, 128)
  const float* kvs = (const float*)d_in[3];    // (32, 128, 128)
  float* out = (float*)d_out;

  char* ws = (char*)d_ws;
  __bf16* xb = (__bf16*)ws;                      // 1 MB
  __bf16* qd = (__bf16*)(ws + (1u << 20));       // 1 MB each
  __bf16* kd = (__bf16*)(ws + 2u * (1u << 20));
  __bf16* kdT = (__bf16*)(ws + 3u * (1u << 20));
  __bf16* vT = (__bf16*)(ws + 4u * (1u << 20));
  __bf16* kvsT = (__bf16*)(ws + 5u * (1u << 20));
  float* P = (float*)(ws + 6u * (1u << 20));     // KS * 6,291,456 B

  const size_t pbytes = ws_size > 6u * (1u << 20) ? ws_size - 6u * (1u << 20) : 0;
  int KS = 1;
  while (KS < 4 && (size_t)(KS * 2) * 6291456ull <= pbytes) KS *= 2;
  const int kc_len = 4096 / KS;

  prep_kernel<<<384, 256, 0, stream>>>(x, xb, kvs, alpha, kvsT);
  gemm_split_kernel<<<192 * KS, 256, 0, stream>>>(xb, W, P, kc_len);
  reduce_kernel<<<384, 256, 0, stream>>>(P, alpha, qd, kd, kdT, vT, KS);
  heads_kernel<<<256, 128, 0, stream>>>(qd, kd, kdT, vT, kvsT, kvs, alpha, out);
}